// Round 6
// baseline (510.266 us; speedup 1.0000x reference)
//
#include <hip/hip_runtime.h>

typedef __attribute__((ext_vector_type(4))) float float4v;

#define TY    8            // output rows per strip
#define TILE  248          // output cols per wave (lanes 1..62)
#define LDSW  256          // LDS ring row width (64 lanes * 4)

__device__ __forceinline__ float4v ld4(const float* __restrict__ p) {
    return *(const float4v*)p;
}
__device__ __forceinline__ void st4(float* __restrict__ p, float4v v) {
    *(float4v*)p = v;
}
__device__ __forceinline__ float frcp(float x) {
    return __builtin_amdgcn_rcpf(x);
}
__device__ __forceinline__ int iclamp(int v, int lo, int hi) {
    return v < lo ? lo : (v > hi ? hi : v);
}
__device__ __forceinline__ float4v sel4(bool m, float4v v) {
    const float4v z4 = {0.f, 0.f, 0.f, 0.f};
    return m ? v : z4;
}

// Wave-autonomous fused E+H FDTD step, compile-time radius NS, manual 1-deep
// software pipeline: iteration e+1's global inputs are loaded (branchless,
// clamped addr + masked value) into registers BEFORE iteration e's compute,
// so ~12 dwordx4 loads are in flight under every iteration's VALU/LDS work.
// Lanes uniform: all 64 lanes compute E (cols xE = W0+(lane-1)*4, incl. the
// x-halo at lanes 0/63); lanes 1..62 write outputs (248 cols/wave).
template<int NS>
__global__ __launch_bounds__(64) void fdtd_ns(
    const float* __restrict__ ca,   const float* __restrict__ cb,
    const float* __restrict__ cq,
    const float* __restrict__ Ey,   const float* __restrict__ Hx,
    const float* __restrict__ Hz,
    const float* __restrict__ mHxz, const float* __restrict__ mHzx,
    const float* __restrict__ mEyx, const float* __restrict__ mEyz,
    const float* __restrict__ ky,   const float* __restrict__ kyh,
    const float* __restrict__ ay,   const float* __restrict__ ayh,
    const float* __restrict__ by,   const float* __restrict__ byh,
    const float* __restrict__ kx,   const float* __restrict__ kxh,
    const float* __restrict__ ax,   const float* __restrict__ axh,
    const float* __restrict__ bx,   const float* __restrict__ bxh,
    const float* __restrict__ rdyp, const float* __restrict__ rdxp,
    const int* __restrict__ stp,
    float* __restrict__ outEy,   float* __restrict__ outHx,
    float* __restrict__ outHz,   float* __restrict__ outMHxz,
    float* __restrict__ outMHzx, float* __restrict__ outMEyx,
    float* __restrict__ outMEyz,
    int B, int NY, int NX, int NSTRIP, int NWX)
{
    int nsr = stp[0] >> 1;
    if (nsr < 1) nsr = 1; if (nsr > 4) nsr = 4;
    if (nsr != NS) return;

    constexpr int NSLOT = (NS <= 2) ? 4 : 8;   // >= 2*NS
    constexpr int M = NSLOT - 1;
    __shared__ float eyl[NSLOT][LDSW];

    float C[4] = {0.f, 0.f, 0.f, 0.f};
    if constexpr (NS == 1)      { C[0] = 1.f; }
    else if constexpr (NS == 2) { C[0] = 1.125f;        C[1] = -1.f/24.f; }
    else if constexpr (NS == 3) { C[0] = 75.f/64.f;     C[1] = -25.f/384.f;
                                  C[2] = 3.f/640.f; }
    else                        { C[0] = 1225.f/1024.f; C[1] = -245.f/3072.f;
                                  C[2] = 49.f/5120.f;   C[3] = -5.f/7168.f; }

    // XCD swizzle: contiguous idx chunk per XCD (y-adjacent strips share L2)
    const int nwg = NSTRIP * NWX;
    int idx = blockIdx.x;
    if ((nwg & 7) == 0) {
        const int q = nwg >> 3;
        idx = (idx & 7) * q + (idx >> 3);
    }
    const int strip = idx % NSTRIP;
    const int wx    = idx / NSTRIP;
    const int b  = blockIdx.y;
    const int y0 = strip * TY;                 // TY=8 -> y0 & M == 0
    const int lane = (int)threadIdx.x & 63;
    const int xE  = wx * TILE + (lane - 1) * 4;   // lane0: W0-4, lane63: W0+248

    const float rdx = rdxp[0];
    const float rdy = rdyp[0];
    const size_t NXs = (size_t)NX;
    const size_t planeOff = (size_t)b * (size_t)NY * NXs;

    // per-4-col-group x masks (groups are 16B-aligned; NX % 4 == 0)
    const bool mL = (xE >= 4) && (xE <= NX);
    const bool m0 = (xE >= 0) && (xE + 4 <= NX);
    const bool mR = (xE + 8 <= NX);
    const int  cL = iclamp(xE - 4, 0, NX - 4);
    const int  c0 = iclamp(xE,     0, NX - 4);
    const int  cR = iclamp(xE + 4, 0, NX - 4);
    const bool outOK = (lane >= 1) && (lane <= 62) && m0;
    const int  lc = lane * 4;                  // LDS col of this lane's E

    // hoisted row-invariant x coefficients
    float4v rkx, axv, bxv, rkxh, axhv, bxhv;
    {
        float4v t = ld4(kx + c0);
        #pragma unroll
        for (int i = 0; i < 4; ++i) rkx[i] = frcp(t[i]);
        axv = ld4(ax + c0); bxv = ld4(bx + c0);
        t = ld4(kxh + c0);
        #pragma unroll
        for (int i = 0; i < 4; ++i) rkxh[i] = frcp(t[i]);
        axhv = ld4(axh + c0); bxhv = ld4(bxh + c0);
    }

    // register rings (slots compile-time after full unroll); slot(t)=(t+16)&M
    float4v hxr[NSLOT], hzc[NSLOT];
    #pragma unroll
    for (int j = 0; j < NSLOT; ++j) {
        hxr[j] = sel4(false, hxr[j]); hzc[j] = sel4(false, hzc[j]);
    }
    #pragma unroll
    for (int j = 0; j < 2*NS - 1; ++j) {       // Hx rows y0+1-2NS .. y0-1
        const int rr  = y0 + 1 - 2*NS + j;
        const int rrc = iclamp(rr, 0, NY - 1);
        hxr[(1 - 2*NS + j + 16) & M] =
            sel4(rr >= 0 && m0, ld4(Hx + planeOff + (size_t)rrc * NXs + c0));
    }

    // staged inputs for one row-iteration
    struct St {
        float4v hzL, hz0, hzR, ey, mzx, mxz, cav, cbv, hxN, mxv, mzv, cqv;
        float ayv, byv, rky, ayhv, byhv, rkyh;
    };
    auto stage = [&](int e, bool needH) -> St {
        St s;
        const int r   = y0 + e;
        const int rcE = iclamp(r, 0, NY - 1);
        const int rr  = r + NS - 1;
        const int rcr = iclamp(rr, 0, NY - 1);
        const size_t rbE = planeOff + (size_t)rcE * NXs;
        s.hzL = sel4(mL, ld4(Hz + rbE + cL));
        s.hz0 = sel4(m0, ld4(Hz + rbE + c0));
        s.hzR = sel4(mR, ld4(Hz + rbE + cR));
        s.ey  = ld4(Ey   + rbE + c0);          // pointwise: eM masked later
        s.mzx = ld4(mHzx + rbE + c0);
        s.mxz = ld4(mHxz + rbE + c0);
        s.cav = ld4(ca + (size_t)rcE * NXs + c0);
        s.cbv = ld4(cb + (size_t)rcE * NXs + c0);
        s.hxN = sel4(m0 && rr < NY,
                     ld4(Hx + planeOff + (size_t)rcr * NXs + c0));
        s.ayv = ay[rcE]; s.byv = by[rcE]; s.rky = frcp(ky[rcE]);
        if (needH) {                            // e compile-time -> folds
            const int h   = r - NS;
            const int rch = iclamp(h, 0, NY - 1);
            const size_t rbH = planeOff + (size_t)rch * NXs;
            s.mxv = ld4(mEyx + rbH + c0);
            s.mzv = ld4(mEyz + rbH + c0);
            s.cqv = ld4(cq + (size_t)rch * NXs + c0);
            s.ayhv = ayh[rch]; s.byhv = byh[rch]; s.rkyh = frcp(kyh[rch]);
        } else {
            s.mxv = sel4(false, s.hz0); s.mzv = s.mxv; s.cqv = s.mxv;
            s.ayhv = 0.f; s.byhv = 0.f; s.rkyh = 0.f;
        }
        return s;
    };

    St S = stage(1 - NS, false);
    #pragma unroll
    for (int e = 1 - NS; e <= TY + NS - 1; ++e) {
        const int r = y0 + e;
        const int h = r - NS;
        St cur = S;
        if (e < TY + NS - 1)
            S = stage(e + 1, (e + 1 >= NS) && (e + 1 <= NS + TY - 1));

        // ---- ring advance (slots compile-time) ----
        hxr[(e + NS - 1 + 16) & M] = cur.hxN;
        hzc[(e + 16) & M]          = cur.hz0;

        // ---- E row r ----
        float w[12] = {cur.hzL[0], cur.hzL[1], cur.hzL[2], cur.hzL[3],
                       cur.hz0[0], cur.hz0[1], cur.hz0[2], cur.hz0[3],
                       cur.hzR[0], cur.hzR[1], cur.hzR[2], cur.hzR[3]};
        float dzx[4] = {0,0,0,0}, dxz[4] = {0,0,0,0};
        #pragma unroll
        for (int k = 1; k <= NS; ++k) {
            const float ck = C[k-1];
            #pragma unroll
            for (int i = 0; i < 4; ++i)        // taps x+k-1, x-k
                dzx[i] += ck * (w[i+3+k] - w[i+4-k]);
            float4v up = hxr[(e + k - 1 + 16) & M];
            float4v dn = hxr[(e - k + 16) & M];
            #pragma unroll
            for (int i = 0; i < 4; ++i)
                dxz[i] += ck * (up[i] - dn[i]);
        }
        float4v eM, oMxz, oMzx;
        #pragma unroll
        for (int i = 0; i < 4; ++i) {
            const float dHzdx = dzx[i] * rdx;
            const float dHxdz = dxz[i] * rdy;
            const float mzx_n = bxv[i]  * cur.mzx[i] + axv[i]  * dHzdx;
            const float mxz_n = cur.byv * cur.mxz[i] + cur.ayv * dHxdz;
            eM[i] = cur.cav[i] * cur.ey[i]
                  + cur.cbv[i] * ((dHzdx * rkx[i]  + mzx_n)
                                - (dHxdz * cur.rky + mxz_n));
            oMxz[i] = mxz_n; oMzx[i] = mzx_n;
        }
        const bool rin = (r >= 0) && (r < NY);
        eM = sel4(rin && m0, eM);              // exact zero-pad for ring
        if (e >= 0 && e < TY) {                // compile-time bounds
            if (rin && outOK) {
                const size_t rb = planeOff + (size_t)r * NXs;
                st4(outEy   + rb + xE, eM);
                st4(outMHxz + rb + xE, oMxz);
                st4(outMHzx + rb + xE, oMzx);
            }
        }

        // ---- publish Ey' row r (wave-private; same-wave DS ordering) ----
        st4(&eyl[(e + 16) & M][lc], eM);

        // ---- H row h (taps rows h-NS+1..h+NS = all published) ----
        if (e >= NS) {                         // compile-time
            if (h < NY && outOK) {
                float4v a0 = ld4(&eyl[(e - NS + 16) & M][lc - 4]);
                float4v a1 = ld4(&eyl[(e - NS + 16) & M][lc]);
                float4v a2 = ld4(&eyl[(e - NS + 16) & M][lc + 4]);
                float lw[12] = {a0[0],a0[1],a0[2],a0[3],
                                a1[0],a1[1],a1[2],a1[3],
                                a2[0],a2[1],a2[2],a2[3]};
                float dEdx[4] = {0,0,0,0}, dEdz[4] = {0,0,0,0};
                #pragma unroll
                for (int k = 1; k <= NS; ++k) {
                    const float ck = C[k-1];
                    #pragma unroll
                    for (int i = 0; i < 4; ++i)    // taps x+k, x-k+1
                        dEdx[i] += ck * (lw[i+4+k] - lw[i+5-k]);
                    float4v up = ld4(&eyl[(e - NS + k + 16) & M][lc]);
                    float4v dn = ld4(&eyl[(e - NS - k + 1 + 16) & M][lc]);
                    #pragma unroll
                    for (int i = 0; i < 4; ++i)
                        dEdz[i] += ck * (up[i] - dn[i]);
                }
                float4v hxv = hxr[(e - NS + 16) & M];
                float4v hzv = hzc[(e - NS + 16) & M];
                const size_t hb = planeOff + (size_t)h * NXs;
                float4v oHx, oHz, oMx, oMz;
                #pragma unroll
                for (int i = 0; i < 4; ++i) {
                    const float dz = dEdz[i] * rdy;    // dEy_dz
                    const float dx = dEdx[i] * rdx;    // dEy_dx
                    const float mz_n = cur.byhv * cur.mzv[i] + cur.ayhv * dz;
                    const float mx_n = bxhv[i]  * cur.mxv[i] + axhv[i]  * dx;
                    oHx[i] = hxv[i] - cur.cqv[i] * (dz * cur.rkyh + mz_n);
                    oHz[i] = hzv[i] + cur.cqv[i] * (dx * rkxh[i]  + mx_n);
                    oMx[i] = mx_n; oMz[i] = mz_n;
                }
                st4(outHx   + hb + xE, oHx);
                st4(outHz   + hb + xE, oHz);
                st4(outMEyx + hb + xE, oMx);
                st4(outMEyz + hb + xE, oMz);
            }
        }
    }
}

extern "C" void kernel_launch(void* const* d_in, const int* in_sizes, int n_in,
                              void* d_out, int out_size, void* d_ws, size_t ws_size,
                              hipStream_t stream)
{
    const float* ca   = (const float*)d_in[0];
    const float* cb   = (const float*)d_in[1];
    const float* cq   = (const float*)d_in[2];
    const float* Ey   = (const float*)d_in[3];
    const float* Hx   = (const float*)d_in[4];
    const float* Hz   = (const float*)d_in[5];
    const float* mHxz = (const float*)d_in[6];
    const float* mHzx = (const float*)d_in[7];
    const float* mEyx = (const float*)d_in[8];
    const float* mEyz = (const float*)d_in[9];
    const float* ky   = (const float*)d_in[10];
    const float* kyh  = (const float*)d_in[11];
    const float* ay   = (const float*)d_in[12];
    const float* ayh  = (const float*)d_in[13];
    const float* by   = (const float*)d_in[14];
    const float* byh  = (const float*)d_in[15];
    const float* kx   = (const float*)d_in[16];
    const float* kxh  = (const float*)d_in[17];
    const float* ax   = (const float*)d_in[18];
    const float* axh  = (const float*)d_in[19];
    const float* bx   = (const float*)d_in[20];
    const float* bxh  = (const float*)d_in[21];
    const float* rdy  = (const float*)d_in[22];
    const float* rdx  = (const float*)d_in[23];
    const int*   stp  = (const int*)d_in[24];

    const int NX   = in_sizes[16];
    const int NYNX = in_sizes[0];
    const int NY   = NYNX / NX;
    const int B    = in_sizes[3] / NYNX;
    const size_t plane = (size_t)B * (size_t)NYNX;

    float* out     = (float*)d_out;
    float* outEy   = out;
    float* outHx   = out + 1 * plane;
    float* outHz   = out + 2 * plane;
    float* outMHxz = out + 3 * plane;
    float* outMHzx = out + 4 * plane;
    float* outMEyx = out + 5 * plane;
    float* outMEyz = out + 6 * plane;

    const int NSTRIP = (NY + TY - 1) / TY;
    const int NWX    = (NX + TILE - 1) / TILE;

    dim3 grid(NSTRIP * NWX, B);
    dim3 block(64);

    #define LAUNCH(NSV)                                                      \
        fdtd_ns<NSV><<<grid, block, 0, stream>>>(                            \
            ca, cb, cq, Ey, Hx, Hz, mHxz, mHzx, mEyx, mEyz,                  \
            ky, kyh, ay, ayh, by, byh, kx, kxh, ax, axh, bx, bxh,            \
            rdy, rdx, stp,                                                   \
            outEy, outHx, outHz, outMHxz, outMHzx, outMEyx, outMEyz,         \
            B, NY, NX, NSTRIP, NWX)

    LAUNCH(2);   // bench path first (stencil=4)
    LAUNCH(1);
    LAUNCH(3);
    LAUNCH(4);
    #undef LAUNCH
}